// Round 2
// 201.405 us; speedup vs baseline: 1.3291x; 1.3291x over previous
//
#include <hip/hip_runtime.h>

#define F      8192
#define KD     64     // coordinate dimensionality
#define NB     8      // neighbors
#define WROWS  32     // rows per block (all 4 waves share these rows)
#define MKEEP  16     // per-(row,quarter) approx list length (superset of top-8)
#define JQ     4      // column quarters
#define CPR    64     // cols per block-round (4 waves x 16)
#define NROUND ((F / JQ) / CPR)   // 32
#define CAP    96     // per-row candidate buffer capacity per fold interval
#define MARGIN 0.25f  // >> 2x max |d_approx - d_exact| (~0.04)

typedef unsigned long long u64;
typedef unsigned short ushort_t;
typedef __attribute__((ext_vector_type(8))) short bf16x8;  // 8 bf16 = 4 VGPRs
typedef __attribute__((ext_vector_type(4))) float f32x4;

__device__ __forceinline__ u64 pack64(float d, int j) {
    // d >= 0 -> f32 bits order-preserving; u64 ascending == lex (d, j)
    return ((u64)__float_as_uint(d) << 32) | (unsigned)j;
}

__device__ __forceinline__ unsigned bf16rn(float x) {
    unsigned u = __float_as_uint(x);
    return (u + 0x7fffu + ((u >> 16) & 1u)) >> 16;
}

// ---------------------------------------------------------------------------
// Kernel 1: prep. sq (exact ascending-k fmaf chain — recheck uses the same
// chain so dot(i,i)==sq[i] bit-exact => d(i,i)==0), transposed bf16 hi/lo
// split (MFMA fragments = contiguous 16B), transposed fp32 Xt32 for recheck.
// ---------------------------------------------------------------------------
__global__ __launch_bounds__(256) void prep_kernel(const float* __restrict__ crd,
                                                   float* __restrict__ sq,
                                                   ushort_t* __restrict__ XtHi,
                                                   ushort_t* __restrict__ XtLo,
                                                   float* __restrict__ Xt32) {
    const int f = blockIdx.x * 256 + threadIdx.x;
    float acc = 0.f;
#pragma unroll
    for (int kb = 0; kb < 8; ++kb) {
        ushort_t hb[8], lb[8];
        float    xv[8];
#pragma unroll
        for (int u = 0; u < 8; ++u) {
            int k = kb * 8 + u;
            float x = crd[k * F + f];
            acc = fmaf(x, x, acc);
            unsigned h = bf16rn(x);
            float hf = __uint_as_float(h << 16);
            unsigned l = bf16rn(x - hf);       // Dekker split, exact residual
            hb[u] = (ushort_t)h; lb[u] = (ushort_t)l; xv[u] = x;
        }
        *(uint4*)&XtHi[(size_t)f * KD + kb * 8] = *(const uint4*)hb;
        *(uint4*)&XtLo[(size_t)f * KD + kb * 8] = *(const uint4*)lb;
        *(float4*)&Xt32[(size_t)f * KD + kb * 8]     = *(const float4*)&xv[0];
        *(float4*)&Xt32[(size_t)f * KD + kb * 8 + 4] = *(const float4*)&xv[4];
    }
    sq[f] = acc;
}

// ---------------------------------------------------------------------------
// Kernel 2: MFMA distance + approx top-16 per (row, col-quarter).
// R9 theory: the old serial fold's per-thread arrays (u64 L[16] + batch[8] =
// 48 regs) blew the 128-reg unified budget (base state ~110: A-frags 32 +
// B dbuf 32 + acc/sqi/pre/addr) -> compiler spilled them to SCRATCH. The
// insertion sort then was a serial ~200cy-per-access scratch chain executed
// by a half-wave while all 4 waves waited at the fold barrier (~1e5 cyc/blk;
// WRITE_SIZE 29.4MB vs 4MB logical = scratch writeback). Fix: wave-parallel
// fold, NO private arrays: 16 lanes own one sorted list slot per row
// (== MKEEP), all 256 threads fold 16 rows/pass x 2 passes. Per 16-entry
// batch: coalesced ds_read_b64, bitonic sort-16 across lanes (shfl_xor),
// then merge: Lv = min(Lv, reverse(batch)) + 4-stage bitonic clean.
// Ordering semantics identical (packed-u64 lex order on (d, j)).
// ---------------------------------------------------------------------------
__global__ __launch_bounds__(256, 4) void knn_mfma(const ushort_t* __restrict__ XtHi,
                                                   const ushort_t* __restrict__ XtLo,
                                                   const float* __restrict__ sq,
                                                   u64* __restrict__ part) {
    __shared__ u64 buf[WROWS][CAP + 1];     // 24.8 KB
    __shared__ u64 lst[WROWS][MKEEP + 1];   // 4.4 KB
    __shared__ __align__(16) float thr[WROWS];
    __shared__ int cnt[WROWS];

    const int tid  = threadIdx.x;
    const int wave = tid >> 6;
    const int tx   = tid & 63;
    const int quad = tx >> 4;
    const int n    = tx & 15;
    const int blockRow = (blockIdx.x >> 2) * WROWS;
    const int jq    = blockIdx.x & 3;
    const int jbase = jq * (F / JQ);

    if (tid < WROWS) { cnt[tid] = 0; thr[tid] = __int_as_float(0x7f800000); }
#pragma unroll
    for (int e = tid; e < WROWS * MKEEP; e += 256) lst[e >> 4][e & 15] = ~0ULL;
    __syncthreads();

    // A fragments for both 16-row tiles, resident all sweep
    const size_t a0 = (size_t)(blockRow + n) * KD + quad * 8;
    const size_t a1 = (size_t)(blockRow + 16 + n) * KD + quad * 8;
    const bf16x8 a0h0 = *(const bf16x8*)(XtHi + a0), a0h1 = *(const bf16x8*)(XtHi + a0 + 32);
    const bf16x8 a0l0 = *(const bf16x8*)(XtLo + a0), a0l1 = *(const bf16x8*)(XtLo + a0 + 32);
    const bf16x8 a1h0 = *(const bf16x8*)(XtHi + a1), a1h1 = *(const bf16x8*)(XtHi + a1 + 32);
    const bf16x8 a1l0 = *(const bf16x8*)(XtLo + a1), a1l1 = *(const bf16x8*)(XtLo + a1 + 32);
    const f32x4 sqi0 = *(const f32x4*)&sq[blockRow + quad * 4];
    const f32x4 sqi1 = *(const f32x4*)&sq[blockRow + 16 + quad * 4];
    f32x4 pre0, pre1;   // 0.5*(sqi - thr); -inf => accept-all
#pragma unroll
    for (int r = 0; r < 4; ++r) { pre0[r] = -__int_as_float(0x7f800000);
                                  pre1[r] = -__int_as_float(0x7f800000); }

    const int laneCol = wave * 16 + n;    // col offset within a round's 64

#define LOADB(H0, H1, L0, L1, SJ, RND)                                        \
    {   int jc = jbase + (RND) * CPR + laneCol;                               \
        size_t bo = (size_t)jc * KD + quad * 8;                               \
        H0 = *(const bf16x8*)(XtHi + bo); H1 = *(const bf16x8*)(XtHi + bo + 32); \
        L0 = *(const bf16x8*)(XtLo + bo); L1 = *(const bf16x8*)(XtLo + bo + 32); \
        SJ = sq[jc]; }

#define MFMABODY(H0, H1, L0, L1)                                              \
        f32x4 za0 = {0,0,0,0}, zb0 = {0,0,0,0}, za1 = {0,0,0,0}, zb1 = {0,0,0,0}; \
        za0 = __builtin_amdgcn_mfma_f32_16x16x32_bf16(a0h0, H0, za0, 0, 0, 0); \
        za0 = __builtin_amdgcn_mfma_f32_16x16x32_bf16(a0h1, H1, za0, 0, 0, 0); \
        zb0 = __builtin_amdgcn_mfma_f32_16x16x32_bf16(a0h0, L0, zb0, 0, 0, 0); \
        zb0 = __builtin_amdgcn_mfma_f32_16x16x32_bf16(a0h1, L1, zb0, 0, 0, 0); \
        zb0 = __builtin_amdgcn_mfma_f32_16x16x32_bf16(a0l0, H0, zb0, 0, 0, 0); \
        zb0 = __builtin_amdgcn_mfma_f32_16x16x32_bf16(a0l1, H1, zb0, 0, 0, 0); \
        za1 = __builtin_amdgcn_mfma_f32_16x16x32_bf16(a1h0, H0, za1, 0, 0, 0); \
        za1 = __builtin_amdgcn_mfma_f32_16x16x32_bf16(a1h1, H1, za1, 0, 0, 0); \
        zb1 = __builtin_amdgcn_mfma_f32_16x16x32_bf16(a1h0, L0, zb1, 0, 0, 0); \
        zb1 = __builtin_amdgcn_mfma_f32_16x16x32_bf16(a1h1, L1, zb1, 0, 0, 0); \
        zb1 = __builtin_amdgcn_mfma_f32_16x16x32_bf16(a1l0, H0, zb1, 0, 0, 0); \
        zb1 = __builtin_amdgcn_mfma_f32_16x16x32_bf16(a1l1, H1, zb1, 0, 0, 0);

// round 0: accept-all, deterministic slot = laneCol (no atomics)
#define PROCESS0(H0, H1, L0, L1, SJ, RND)                                     \
    {   MFMABODY(H0, H1, L0, L1)                                              \
        const int jc = jbase + (RND) * CPR + laneCol;                         \
        _Pragma("unroll")                                                     \
        for (int r = 0; r < 4; ++r) {                                         \
            float d0 = fmaxf((sqi0[r] + SJ) - 2.f * (za0[r] + zb0[r]), 0.f);  \
            buf[quad * 4 + r][laneCol] = pack64(d0, jc);                      \
            float d1 = fmaxf((sqi1[r] + SJ) - 2.f * (za1[r] + zb1[r]), 0.f);  \
            buf[16 + quad * 4 + r][laneCol] = pack64(d1, jc);                 \
        } }

#define PROCESS(H0, H1, L0, L1, SJ, RND)                                      \
    {   MFMABODY(H0, H1, L0, L1)                                              \
        const int jc = jbase + (RND) * CPR + laneCol;                         \
        const float h = 0.5f * SJ;                                            \
        _Pragma("unroll")                                                     \
        for (int r = 0; r < 4; ++r) {                                         \
            float dot = za0[r] + zb0[r];                                      \
            if (dot >= pre0[r] + h) {                                         \
                float d = fmaxf((sqi0[r] + SJ) - 2.f * dot, 0.f);             \
                int row = quad * 4 + r;                                       \
                int q = atomicAdd(&cnt[row], 1);                              \
                if (q < CAP) buf[row][q] = pack64(d, jc);                     \
            }                                                                 \
            dot = za1[r] + zb1[r];                                            \
            if (dot >= pre1[r] + h) {                                         \
                float d = fmaxf((sqi1[r] + SJ) - 2.f * dot, 0.f);             \
                int row = 16 + quad * 4 + r;                                  \
                int q = atomicAdd(&cnt[row], 1);                              \
                if (q < CAP) buf[row][q] = pack64(d, jc);                     \
            }                                                                 \
        } }

// Wave-parallel fold: no per-thread arrays (no scratch). 16 lanes per row;
// lane n holds list slot n (ascending across lanes). 16 rows per pass,
// 2 passes cover WROWS=32. R0=1 -> round-0 fixed 64 entries, else cnt[row].
#define FOLD(R0)                                                              \
    {   __syncthreads();                                                      \
        _Pragma("unroll")                                                     \
        for (int p = 0; p < 2; ++p) {                                         \
            const int row = p * 16 + wave * 4 + quad;                         \
            u64 Lv = lst[row][n];                                             \
            const int nn = (R0) ? CPR : min(cnt[row], CAP);                   \
            for (int ii = 0; ii < nn; ii += 16) {                             \
                u64 x = (ii + n < nn) ? buf[row][ii + n] : ~0ULL;             \
                /* bitonic sort-16 ascending across lanes n = 0..15 */        \
                _Pragma("unroll")                                             \
                for (int k = 2; k <= 16; k <<= 1) {                           \
                    _Pragma("unroll")                                         \
                    for (int j = k >> 1; j >= 1; j >>= 1) {                   \
                        u64 px = __shfl_xor(x, j, 64);                        \
                        bool wmin = ((n & j) == 0) == ((n & k) == 0);         \
                        x = (wmin == (px < x)) ? px : x;                      \
                    }                                                         \
                }                                                             \
                /* merge: keep 16 smallest of (Lv asc, x asc) */              \
                u64 xr = __shfl_xor(x, 15, 64);   /* reverse within 16 */     \
                Lv = (xr < Lv) ? xr : Lv;         /* bitonic now */           \
                _Pragma("unroll")                                             \
                for (int j = 8; j >= 1; j >>= 1) {                            \
                    u64 pl = __shfl_xor(Lv, j, 64);                           \
                    bool wmin = ((n & j) == 0);                               \
                    Lv = (wmin == (pl < Lv)) ? pl : Lv;                       \
                }                                                             \
            }                                                                 \
            lst[row][n] = Lv;                                                 \
            if (n == NB - 1) thr[row] = __uint_as_float((unsigned)(Lv >> 32)) + MARGIN; \
            if (n == 0) cnt[row] = 0;                                         \
        }                                                                     \
        __syncthreads();                                                      \
        {   f32x4 t0 = *(const f32x4*)&thr[quad * 4];                         \
            f32x4 t1 = *(const f32x4*)&thr[16 + quad * 4];                    \
            _Pragma("unroll")                                                 \
            for (int r = 0; r < 4; ++r) {                                     \
                pre0[r] = 0.5f * (sqi0[r] - t0[r]);                           \
                pre1[r] = 0.5f * (sqi1[r] - t1[r]);                           \
            } } }

    bf16x8 B0h0, B0h1, B0l0, B0l1, B1h0, B1h1, B1l0, B1l1;
    float  B0sj, B1sj;
    LOADB(B0h0, B0h1, B0l0, B0l1, B0sj, 0)
    LOADB(B1h0, B1h1, B1l0, B1l1, B1sj, 1)

    PROCESS0(B0h0, B0h1, B0l0, B0l1, B0sj, 0)
    LOADB(B0h0, B0h1, B0l0, B0l1, B0sj, 2)
    FOLD(1)
    PROCESS(B1h0, B1h1, B1l0, B1l1, B1sj, 1)
    LOADB(B1h0, B1h1, B1l0, B1l1, B1sj, 3)
    FOLD(0)

    for (int rr = 2; rr < NROUND; rr += 2) {
        PROCESS(B0h0, B0h1, B0l0, B0l1, B0sj, rr)
        if (rr + 2 < NROUND) LOADB(B0h0, B0h1, B0l0, B0l1, B0sj, rr + 2)
        PROCESS(B1h0, B1h1, B1l0, B1l1, B1sj, rr + 1)
        if (rr + 3 < NROUND) LOADB(B1h0, B1h1, B1l0, B1l1, B1sj, rr + 3)
        if (((rr + 1) & (rr + 2)) == 0) FOLD(0)   // rounds 3,7,15,31
    }

    // write per-quarter top-16 lists (final fold happened at round 31)
#pragma unroll
    for (int e = tid; e < WROWS * MKEEP; e += 256) {
        int rrw = e >> 4, ss = e & 15;
        part[((size_t)jq * F + blockRow + rrw) * MKEEP + ss] = lst[rrw][ss];
    }
#undef LOADB
#undef MFMABODY
#undef PROCESS0
#undef PROCESS
#undef FOLD
}

// ---------------------------------------------------------------------------
// Kernel 3: exact recheck. Block = 4 rows x 64 candidates (one row per wave).
// B rows contiguous from Xt32 (256B/candidate, L2-hot); A row in LDS.
// Exact ascending-k fmaf chain (bit-identical to sq's => d(i,i)==0).
// Top-8 via in-register wave shuffle-pop on packed u64 -> exact jax tie-break.
// ---------------------------------------------------------------------------
__global__ __launch_bounds__(256) void recheck_kernel(const float* __restrict__ Xt32,
                                                      const float* __restrict__ sq,
                                                      const u64* __restrict__ part,
                                                      int* __restrict__ knn) {
    __shared__ float A_s[4][KD];
    const int tid = threadIdx.x;
    const int rl = tid >> 6, tx = tid & 63;
    const int i = blockIdx.x * 4 + rl;

    A_s[tid >> 6][tid & 63] = Xt32[(size_t)(blockIdx.x * 4 + (tid >> 6)) * KD + (tid & 63)];
    __syncthreads();

    u64 pc = part[((size_t)(tx >> 4) * F + i) * MKEEP + (tx & 15)];
    int j = (int)(pc & 0xffffffffu);

    const float4* b4 = (const float4*)(Xt32 + (size_t)j * KD);
    float acc = 0.f;
#pragma unroll
    for (int kk = 0; kk < KD / 4; ++kk) {
        float4 b = b4[kk];
        const float* a = &A_s[rl][kk * 4];
        acc = fmaf(a[0], b.x, acc);
        acc = fmaf(a[1], b.y, acc);
        acc = fmaf(a[2], b.z, acc);
        acc = fmaf(a[3], b.w, acc);
    }
    float d = fmaxf((sq[i] + sq[j]) - 2.f * acc, 0.f);
    u64 mine = pack64(d, j);

    int myout = 0;
#pragma unroll
    for (int s = 0; s < NB; ++s) {
        u64 m = mine;
#pragma unroll
        for (int off = 32; off >= 1; off >>= 1) {
            u64 o = __shfl_xor(m, off, 64);
            if (o < m) m = o;
        }
        if (mine == m) mine = ~0ULL;       // pop (unique (d,j) per row)
        if (tx == s) myout = (int)(m & 0xffffffffu);
    }
    if (tx < NB) knn[(size_t)i * NB + tx] = myout;
}

// ---------------------------------------------------------------------------
// Kernel 4: gather. 4 blocks per (b,c); row staged in LDS; int4 knn +
// float4 stores, coalesced.
// ---------------------------------------------------------------------------
__global__ __launch_bounds__(512) void gather_kernel(const float* __restrict__ inp,
                                                     const int* __restrict__ knn,
                                                     float* __restrict__ out) {
    __shared__ float row[F];    // 32 KB
    const int bc    = blockIdx.x >> 2;
    const int chunk = blockIdx.x & 3;
    const int tid   = threadIdx.x;

    const float4* in4  = (const float4*)(inp + (size_t)bc * F);
    float4*       row4 = (float4*)row;
#pragma unroll
    for (int i = 0; i < (F / 4) / 512; ++i) row4[i * 512 + tid] = in4[i * 512 + tid];
    __syncthreads();

    const int4* kn4 = (const int4*)knn;
    float4*     ou4 = (float4*)(out + (size_t)bc * (F * NB));

#pragma unroll
    for (int i = 0; i < 8; ++i) {
        int e = chunk * 4096 + i * 512 + tid;
        int4 idx = kn4[e];
        if (e == 0) idx.x = 0;             // flat_idx[0] hardcoded 0
        float4 o;
        o.x = row[idx.x]; o.y = row[idx.y]; o.z = row[idx.z]; o.w = row[idx.w];
        ou4[e] = o;
    }
}

extern "C" void kernel_launch(void* const* d_in, const int* in_sizes, int n_in,
                              void* d_out, int out_size, void* d_ws, size_t ws_size,
                              hipStream_t stream) {
    const float* inp = (const float*)d_in[0];   // (64,4,8192,1) fp32
    const float* crd = (const float*)d_in[1];   // (64,1,8192)  fp32
    float* out = (float*)d_out;                 // (64,4,65536,1) fp32

    ushort_t* XtHi = (ushort_t*)d_ws;                               // 1 MB
    ushort_t* XtLo = (ushort_t*)((char*)d_ws + (1u << 20));         // 1 MB
    float*    Xt32 = (float*)((char*)d_ws + (2u << 20));            // 2 MB
    float*    sq   = (float*)((char*)d_ws + (4u << 20));            // 32 KB
    int*      knn  = (int*)((char*)d_ws + (4u << 20) + (1u << 15)); // 256 KB
    u64*      part = (u64*)((char*)d_ws + (5u << 20));              // 4 MB

    prep_kernel<<<F / 256, 256, 0, stream>>>(crd, sq, XtHi, XtLo, Xt32);
    knn_mfma<<<(F / WROWS) * JQ, 256, 0, stream>>>(XtHi, XtLo, sq, part);
    recheck_kernel<<<F / 4, 256, 0, stream>>>(Xt32, sq, part, knn);
    gather_kernel<<<256 * 4, 512, 0, stream>>>(inp, knn, out);
}

// Round 5
// 191.376 us; speedup vs baseline: 1.3988x; 1.0524x over previous
//
#include <hip/hip_runtime.h>

#define F      8192
#define KD     64     // coordinate dimensionality
#define NB     8      // neighbors
#define WROWS  32     // rows per block (all 4 waves share these rows)
#define MKEEP  16     // per-(row,quarter) approx list length (superset of top-8)
#define JQ     4      // column quarters
#define CPR    64     // cols per block-round (4 waves x 16)
#define NROUND ((F / JQ) / CPR)   // 32
#define CAP    96     // per-row candidate buffer capacity per fold interval
#define MARGIN 0.25f  // >> 2x max |d_approx - d_exact| (~0.04)

typedef unsigned long long u64;
typedef unsigned short ushort_t;
typedef __attribute__((ext_vector_type(8))) short bf16x8;  // 8 bf16 = 4 VGPRs
typedef __attribute__((ext_vector_type(4))) float f32x4;

__device__ __forceinline__ u64 pack64(float d, int j) {
    // d >= 0 -> f32 bits order-preserving; u64 ascending == lex (d, j)
    return ((u64)__float_as_uint(d) << 32) | (unsigned)j;
}

__device__ __forceinline__ unsigned bf16rn(float x) {
    unsigned u = __float_as_uint(x);
    return (u + 0x7fffu + ((u >> 16) & 1u)) >> 16;
}

// ---------------------------------------------------------------------------
// DPP-based 16-lane exchanges. All fold shuffles stay within a 16-lane group
// == one DPP row on CDNA; exec divergence is row-uniform, so DPP never reads
// inactive lanes. R4 FIX: DPP direction convention — per GCN ISA (and LLVM's
// row_shr:1/2/4/8 prefix-scan idiom), row_shr:N = dest[i] <- src[i-N],
// row_shl:N = dest[i] <- src[i+N]. R3 had the selects swapped for xor4/xor8
// (absmax 7.14). xor1/xor2 (quad_perm) and mirror are direction-symmetric.
// ---------------------------------------------------------------------------
template<int CTRL>
__device__ __forceinline__ u64 dpp_u64(u64 x) {
    unsigned lo = (unsigned)x, hi = (unsigned)(x >> 32);
    lo = (unsigned)__builtin_amdgcn_update_dpp(0, (int)lo, CTRL, 0xF, 0xF, true);
    hi = (unsigned)__builtin_amdgcn_update_dpp(0, (int)hi, CTRL, 0xF, 0xF, true);
    return ((u64)hi << 32) | lo;
}
// quad_perm [1,0,3,2] = 0xB1 (xor1); [2,3,0,1] = 0x4E (xor2)
__device__ __forceinline__ u64 swap_xor1(u64 x) { return dpp_u64<0xB1>(x); }
__device__ __forceinline__ u64 swap_xor2(u64 x) { return dpp_u64<0x4E>(x); }
// xor4: (n&4)==0 lanes need src[n+4] -> row_shl:4 (0x104);
//       (n&4)!=0 lanes need src[n-4] -> row_shr:4 (0x114)
__device__ __forceinline__ u64 swap_xor4(u64 x, int n) {
    u64 shr = dpp_u64<0x114>(x);   // src[n-4]
    u64 shl = dpp_u64<0x104>(x);   // src[n+4]
    return (n & 4) ? shr : shl;
}
// xor8: (n&8)==0 -> row_shl:8 (0x108) = src[n+8]; else row_shr:8 (0x118) = src[n-8]
__device__ __forceinline__ u64 swap_xor8(u64 x, int n) {
    u64 shr = dpp_u64<0x118>(x);   // src[n-8]
    u64 shl = dpp_u64<0x108>(x);   // src[n+8]
    return (n & 8) ? shr : shl;
}
// xor15 within 16-lane row: row_mirror (0x140)
__device__ __forceinline__ u64 swap_mirror(u64 x) { return dpp_u64<0x140>(x); }

// compare-exchange stages (ascending bitonic over lanes n=0..15)
#define CEK(x, J, K, SW)                                                      \
    { u64 px = SW; bool wmin = ((n & (J)) == 0) == ((n & (K)) == 0);          \
      x = (wmin == (px < x)) ? px : x; }
#define CEA(L, J, SW)                                                         \
    { u64 pl = SW; bool wmin = ((n & (J)) == 0);                              \
      L = (wmin == (pl < L)) ? pl : L; }
#define SORT16(x)                                                             \
    CEK(x, 1, 2,  swap_xor1(x))                                               \
    CEK(x, 2, 4,  swap_xor2(x))    CEK(x, 1, 4,  swap_xor1(x))                \
    CEK(x, 4, 8,  swap_xor4(x,n))  CEK(x, 2, 8,  swap_xor2(x))                \
    CEK(x, 1, 8,  swap_xor1(x))                                               \
    CEK(x, 8, 16, swap_xor8(x,n))  CEK(x, 4, 16, swap_xor4(x,n))              \
    CEK(x, 2, 16, swap_xor2(x))    CEK(x, 1, 16, swap_xor1(x))

// ---------------------------------------------------------------------------
// Kernel 1: prep. sq (exact ascending-k fmaf chain — recheck uses the same
// chain so dot(i,i)==sq[i] bit-exact => d(i,i)==0), transposed bf16 hi/lo
// split (MFMA fragments = contiguous 16B), transposed fp32 Xt32 for recheck.
// ---------------------------------------------------------------------------
__global__ __launch_bounds__(256) void prep_kernel(const float* __restrict__ crd,
                                                   float* __restrict__ sq,
                                                   ushort_t* __restrict__ XtHi,
                                                   ushort_t* __restrict__ XtLo,
                                                   float* __restrict__ Xt32) {
    const int f = blockIdx.x * 256 + threadIdx.x;
    float acc = 0.f;
#pragma unroll
    for (int kb = 0; kb < 8; ++kb) {
        ushort_t hb[8], lb[8];
        float    xv[8];
#pragma unroll
        for (int u = 0; u < 8; ++u) {
            int k = kb * 8 + u;
            float x = crd[k * F + f];
            acc = fmaf(x, x, acc);
            unsigned h = bf16rn(x);
            float hf = __uint_as_float(h << 16);
            unsigned l = bf16rn(x - hf);       // Dekker split, exact residual
            hb[u] = (ushort_t)h; lb[u] = (ushort_t)l; xv[u] = x;
        }
        *(uint4*)&XtHi[(size_t)f * KD + kb * 8] = *(const uint4*)hb;
        *(uint4*)&XtLo[(size_t)f * KD + kb * 8] = *(const uint4*)lb;
        *(float4*)&Xt32[(size_t)f * KD + kb * 8]     = *(const float4*)&xv[0];
        *(float4*)&Xt32[(size_t)f * KD + kb * 8 + 4] = *(const float4*)&xv[4];
    }
    sq[f] = acc;
}

// ---------------------------------------------------------------------------
// Kernel 2: MFMA distance + approx top-16 per (row, col-quarter).
// R9: wave-parallel fold (no private arrays -> no scratch; WRITE_SIZE
// 29.4->9.2MB confirmed). R10/R4: fold stages via DPP (VALU pipe, ~5x lower
// stage latency than ds_bpermute chains) + per-batch skip: batch is sorted
// only if some element beats the pass-start 16th-best (tmax, conservative
// since the list only shrinks -> skip is safe). Ordering semantics identical
// (packed-u64 lex order on (d, j)).
// ---------------------------------------------------------------------------
__global__ __launch_bounds__(256, 4) void knn_mfma(const ushort_t* __restrict__ XtHi,
                                                   const ushort_t* __restrict__ XtLo,
                                                   const float* __restrict__ sq,
                                                   u64* __restrict__ part) {
    __shared__ u64 buf[WROWS][CAP + 1];     // 24.8 KB
    __shared__ u64 lst[WROWS][MKEEP + 1];   // 4.4 KB
    __shared__ __align__(16) float thr[WROWS];
    __shared__ int cnt[WROWS];

    const int tid  = threadIdx.x;
    const int wave = tid >> 6;
    const int tx   = tid & 63;
    const int quad = tx >> 4;
    const int n    = tx & 15;
    const int blockRow = (blockIdx.x >> 2) * WROWS;
    const int jq    = blockIdx.x & 3;
    const int jbase = jq * (F / JQ);

    if (tid < WROWS) { cnt[tid] = 0; thr[tid] = __int_as_float(0x7f800000); }
#pragma unroll
    for (int e = tid; e < WROWS * MKEEP; e += 256) lst[e >> 4][e & 15] = ~0ULL;
    __syncthreads();

    // A fragments for both 16-row tiles, resident all sweep
    const size_t a0 = (size_t)(blockRow + n) * KD + quad * 8;
    const size_t a1 = (size_t)(blockRow + 16 + n) * KD + quad * 8;
    const bf16x8 a0h0 = *(const bf16x8*)(XtHi + a0), a0h1 = *(const bf16x8*)(XtHi + a0 + 32);
    const bf16x8 a0l0 = *(const bf16x8*)(XtLo + a0), a0l1 = *(const bf16x8*)(XtLo + a0 + 32);
    const bf16x8 a1h0 = *(const bf16x8*)(XtHi + a1), a1h1 = *(const bf16x8*)(XtHi + a1 + 32);
    const bf16x8 a1l0 = *(const bf16x8*)(XtLo + a1), a1l1 = *(const bf16x8*)(XtLo + a1 + 32);
    const f32x4 sqi0 = *(const f32x4*)&sq[blockRow + quad * 4];
    const f32x4 sqi1 = *(const f32x4*)&sq[blockRow + 16 + quad * 4];
    f32x4 pre0, pre1;   // 0.5*(sqi - thr); -inf => accept-all
#pragma unroll
    for (int r = 0; r < 4; ++r) { pre0[r] = -__int_as_float(0x7f800000);
                                  pre1[r] = -__int_as_float(0x7f800000); }

    const int laneCol = wave * 16 + n;    // col offset within a round's 64

#define LOADB(H0, H1, L0, L1, SJ, RND)                                        \
    {   int jc = jbase + (RND) * CPR + laneCol;                               \
        size_t bo = (size_t)jc * KD + quad * 8;                               \
        H0 = *(const bf16x8*)(XtHi + bo); H1 = *(const bf16x8*)(XtHi + bo + 32); \
        L0 = *(const bf16x8*)(XtLo + bo); L1 = *(const bf16x8*)(XtLo + bo + 32); \
        SJ = sq[jc]; }

#define MFMABODY(H0, H1, L0, L1)                                              \
        f32x4 za0 = {0,0,0,0}, zb0 = {0,0,0,0}, za1 = {0,0,0,0}, zb1 = {0,0,0,0}; \
        za0 = __builtin_amdgcn_mfma_f32_16x16x32_bf16(a0h0, H0, za0, 0, 0, 0); \
        za0 = __builtin_amdgcn_mfma_f32_16x16x32_bf16(a0h1, H1, za0, 0, 0, 0); \
        zb0 = __builtin_amdgcn_mfma_f32_16x16x32_bf16(a0h0, L0, zb0, 0, 0, 0); \
        zb0 = __builtin_amdgcn_mfma_f32_16x16x32_bf16(a0h1, L1, zb0, 0, 0, 0); \
        zb0 = __builtin_amdgcn_mfma_f32_16x16x32_bf16(a0l0, H0, zb0, 0, 0, 0); \
        zb0 = __builtin_amdgcn_mfma_f32_16x16x32_bf16(a0l1, H1, zb0, 0, 0, 0); \
        za1 = __builtin_amdgcn_mfma_f32_16x16x32_bf16(a1h0, H0, za1, 0, 0, 0); \
        za1 = __builtin_amdgcn_mfma_f32_16x16x32_bf16(a1h1, H1, za1, 0, 0, 0); \
        zb1 = __builtin_amdgcn_mfma_f32_16x16x32_bf16(a1h0, L0, zb1, 0, 0, 0); \
        zb1 = __builtin_amdgcn_mfma_f32_16x16x32_bf16(a1h1, L1, zb1, 0, 0, 0); \
        zb1 = __builtin_amdgcn_mfma_f32_16x16x32_bf16(a1l0, H0, zb1, 0, 0, 0); \
        zb1 = __builtin_amdgcn_mfma_f32_16x16x32_bf16(a1l1, H1, zb1, 0, 0, 0);

// round 0: accept-all, deterministic slot = laneCol (no atomics)
#define PROCESS0(H0, H1, L0, L1, SJ, RND)                                     \
    {   MFMABODY(H0, H1, L0, L1)                                              \
        const int jc = jbase + (RND) * CPR + laneCol;                         \
        _Pragma("unroll")                                                     \
        for (int r = 0; r < 4; ++r) {                                         \
            float d0 = fmaxf((sqi0[r] + SJ) - 2.f * (za0[r] + zb0[r]), 0.f);  \
            buf[quad * 4 + r][laneCol] = pack64(d0, jc);                      \
            float d1 = fmaxf((sqi1[r] + SJ) - 2.f * (za1[r] + zb1[r]), 0.f);  \
            buf[16 + quad * 4 + r][laneCol] = pack64(d1, jc);                 \
        } }

#define PROCESS(H0, H1, L0, L1, SJ, RND)                                      \
    {   MFMABODY(H0, H1, L0, L1)                                              \
        const int jc = jbase + (RND) * CPR + laneCol;                         \
        const float h = 0.5f * SJ;                                            \
        _Pragma("unroll")                                                     \
        for (int r = 0; r < 4; ++r) {                                         \
            float dot = za0[r] + zb0[r];                                      \
            if (dot >= pre0[r] + h) {                                         \
                float d = fmaxf((sqi0[r] + SJ) - 2.f * dot, 0.f);             \
                int row = quad * 4 + r;                                       \
                int q = atomicAdd(&cnt[row], 1);                              \
                if (q < CAP) buf[row][q] = pack64(d, jc);                     \
            }                                                                 \
            dot = za1[r] + zb1[r];                                            \
            if (dot >= pre1[r] + h) {                                         \
                float d = fmaxf((sqi1[r] + SJ) - 2.f * dot, 0.f);             \
                int row = 16 + quad * 4 + r;                                  \
                int q = atomicAdd(&cnt[row], 1);                              \
                if (q < CAP) buf[row][q] = pack64(d, jc);                     \
            }                                                                 \
        } }

// Wave-parallel fold, DPP stages. 16 lanes per row; lane n holds sorted list
// slot n. 16 rows per pass, 2 passes cover WROWS=32. Per 16-entry batch:
// ballot pre-skip vs pass-start 16th-best (conservative -> safe), bitonic
// sort-16 (10 DPP stages), merge Lv=min(Lv,mirror(batch)) + 4 clean stages.
#define FOLD(R0)                                                              \
    {   __syncthreads();                                                      \
        _Pragma("unroll")                                                     \
        for (int p = 0; p < 2; ++p) {                                         \
            const int row = p * 16 + wave * 4 + quad;                         \
            u64 Lv = lst[row][n];                                             \
            const u64 tmax = __shfl(Lv, (tx & 48) | 15, 64);                  \
            const int nn = (R0) ? CPR : min(cnt[row], CAP);                   \
            for (int ii = 0; ii < nn; ii += 16) {                             \
                u64 x = (ii + n < nn) ? buf[row][ii + n] : ~0ULL;             \
                u64 bal = __ballot(x < tmax);                                 \
                if ((unsigned short)(bal >> (quad * 16)) == 0) continue;      \
                SORT16(x)                                                     \
                u64 xr = swap_mirror(x);      /* reverse within 16 */         \
                Lv = (xr < Lv) ? xr : Lv;     /* bitonic now */               \
                CEA(Lv, 8, swap_xor8(Lv, n))                                  \
                CEA(Lv, 4, swap_xor4(Lv, n))                                  \
                CEA(Lv, 2, swap_xor2(Lv))                                     \
                CEA(Lv, 1, swap_xor1(Lv))                                     \
            }                                                                 \
            lst[row][n] = Lv;                                                 \
            if (n == NB - 1) thr[row] = __uint_as_float((unsigned)(Lv >> 32)) + MARGIN; \
            if (n == 0) cnt[row] = 0;                                         \
        }                                                                     \
        __syncthreads();                                                      \
        {   f32x4 t0 = *(const f32x4*)&thr[quad * 4];                         \
            f32x4 t1 = *(const f32x4*)&thr[16 + quad * 4];                    \
            _Pragma("unroll")                                                 \
            for (int r = 0; r < 4; ++r) {                                     \
                pre0[r] = 0.5f * (sqi0[r] - t0[r]);                           \
                pre1[r] = 0.5f * (sqi1[r] - t1[r]);                           \
            } } }

    bf16x8 B0h0, B0h1, B0l0, B0l1, B1h0, B1h1, B1l0, B1l1;
    float  B0sj, B1sj;
    LOADB(B0h0, B0h1, B0l0, B0l1, B0sj, 0)
    LOADB(B1h0, B1h1, B1l0, B1l1, B1sj, 1)

    PROCESS0(B0h0, B0h1, B0l0, B0l1, B0sj, 0)
    LOADB(B0h0, B0h1, B0l0, B0l1, B0sj, 2)
    FOLD(1)
    PROCESS(B1h0, B1h1, B1l0, B1l1, B1sj, 1)
    LOADB(B1h0, B1h1, B1l0, B1l1, B1sj, 3)
    FOLD(0)

    for (int rr = 2; rr < NROUND; rr += 2) {
        PROCESS(B0h0, B0h1, B0l0, B0l1, B0sj, rr)
        if (rr + 2 < NROUND) LOADB(B0h0, B0h1, B0l0, B0l1, B0sj, rr + 2)
        PROCESS(B1h0, B1h1, B1l0, B1l1, B1sj, rr + 1)
        if (rr + 3 < NROUND) LOADB(B1h0, B1h1, B1l0, B1l1, B1sj, rr + 3)
        if (((rr + 1) & (rr + 2)) == 0) FOLD(0)   // rounds 3,7,15,31
    }

    // write per-quarter top-16 lists (final fold happened at round 31)
#pragma unroll
    for (int e = tid; e < WROWS * MKEEP; e += 256) {
        int rrw = e >> 4, ss = e & 15;
        part[((size_t)jq * F + blockRow + rrw) * MKEEP + ss] = lst[rrw][ss];
    }
#undef LOADB
#undef MFMABODY
#undef PROCESS0
#undef PROCESS
#undef FOLD
}

// ---------------------------------------------------------------------------
// Kernel 3: exact recheck. Block = 4 rows x 64 candidates (one row per wave).
// B rows contiguous from Xt32 (256B/candidate, L2-hot); A row in LDS.
// Exact ascending-k fmaf chain (bit-identical to sq's => d(i,i)==0).
// Top-8 via in-register wave shuffle-pop on packed u64 -> exact jax tie-break.
// ---------------------------------------------------------------------------
__global__ __launch_bounds__(256) void recheck_kernel(const float* __restrict__ Xt32,
                                                      const float* __restrict__ sq,
                                                      const u64* __restrict__ part,
                                                      int* __restrict__ knn) {
    __shared__ float A_s[4][KD];
    const int tid = threadIdx.x;
    const int rl = tid >> 6, tx = tid & 63;
    const int i = blockIdx.x * 4 + rl;

    A_s[tid >> 6][tid & 63] = Xt32[(size_t)(blockIdx.x * 4 + (tid >> 6)) * KD + (tid & 63)];
    __syncthreads();

    u64 pc = part[((size_t)(tx >> 4) * F + i) * MKEEP + (tx & 15)];
    int j = (int)(pc & 0xffffffffu);

    const float4* b4 = (const float4*)(Xt32 + (size_t)j * KD);
    float acc = 0.f;
#pragma unroll
    for (int kk = 0; kk < KD / 4; ++kk) {
        float4 b = b4[kk];
        const float* a = &A_s[rl][kk * 4];
        acc = fmaf(a[0], b.x, acc);
        acc = fmaf(a[1], b.y, acc);
        acc = fmaf(a[2], b.z, acc);
        acc = fmaf(a[3], b.w, acc);
    }
    float d = fmaxf((sq[i] + sq[j]) - 2.f * acc, 0.f);
    u64 mine = pack64(d, j);

    int myout = 0;
#pragma unroll
    for (int s = 0; s < NB; ++s) {
        u64 m = mine;
#pragma unroll
        for (int off = 32; off >= 1; off >>= 1) {
            u64 o = __shfl_xor(m, off, 64);
            if (o < m) m = o;
        }
        if (mine == m) mine = ~0ULL;       // pop (unique (d,j) per row)
        if (tx == s) myout = (int)(m & 0xffffffffu);
    }
    if (tx < NB) knn[(size_t)i * NB + tx] = myout;
}

// ---------------------------------------------------------------------------
// Kernel 4: gather. 4 blocks per (b,c); row staged in LDS; int4 knn +
// float4 stores, coalesced.
// ---------------------------------------------------------------------------
__global__ __launch_bounds__(512) void gather_kernel(const float* __restrict__ inp,
                                                     const int* __restrict__ knn,
                                                     float* __restrict__ out) {
    __shared__ float row[F];    // 32 KB
    const int bc    = blockIdx.x >> 2;
    const int chunk = blockIdx.x & 3;
    const int tid   = threadIdx.x;

    const float4* in4  = (const float4*)(inp + (size_t)bc * F);
    float4*       row4 = (float4*)row;
#pragma unroll
    for (int i = 0; i < (F / 4) / 512; ++i) row4[i * 512 + tid] = in4[i * 512 + tid];
    __syncthreads();

    const int4* kn4 = (const int4*)knn;
    float4*     ou4 = (float4*)(out + (size_t)bc * (F * NB));

#pragma unroll
    for (int i = 0; i < 8; ++i) {
        int e = chunk * 4096 + i * 512 + tid;
        int4 idx = kn4[e];
        if (e == 0) idx.x = 0;             // flat_idx[0] hardcoded 0
        float4 o;
        o.x = row[idx.x]; o.y = row[idx.y]; o.z = row[idx.z]; o.w = row[idx.w];
        ou4[e] = o;
    }
}

extern "C" void kernel_launch(void* const* d_in, const int* in_sizes, int n_in,
                              void* d_out, int out_size, void* d_ws, size_t ws_size,
                              hipStream_t stream) {
    const float* inp = (const float*)d_in[0];   // (64,4,8192,1) fp32
    const float* crd = (const float*)d_in[1];   // (64,1,8192)  fp32
    float* out = (float*)d_out;                 // (64,4,65536,1) fp32

    ushort_t* XtHi = (ushort_t*)d_ws;                               // 1 MB
    ushort_t* XtLo = (ushort_t*)((char*)d_ws + (1u << 20));         // 1 MB
    float*    Xt32 = (float*)((char*)d_ws + (2u << 20));            // 2 MB
    float*    sq   = (float*)((char*)d_ws + (4u << 20));            // 32 KB
    int*      knn  = (int*)((char*)d_ws + (4u << 20) + (1u << 15)); // 256 KB
    u64*      part = (u64*)((char*)d_ws + (5u << 20));              // 4 MB

    prep_kernel<<<F / 256, 256, 0, stream>>>(crd, sq, XtHi, XtLo, Xt32);
    knn_mfma<<<(F / WROWS) * JQ, 256, 0, stream>>>(XtHi, XtLo, sq, part);
    recheck_kernel<<<F / 4, 256, 0, stream>>>(Xt32, sq, part, knn);
    gather_kernel<<<256 * 4, 512, 0, stream>>>(inp, knn, out);
}

// Round 8
// 163.505 us; speedup vs baseline: 1.6372x; 1.1705x over previous
//
#include <hip/hip_runtime.h>

#define F      8192
#define KD     64     // coordinate dimensionality
#define NB     8      // neighbors
#define WROWS  32     // rows per block (all 4 waves share these rows)
#define MKEEP  16     // per-(row,quarter) approx list length (superset of top-8)
#define JQ     4      // column quarters
#define CPR    64     // cols per block-round (4 waves x 16)
#define NROUND ((F / JQ) / CPR)   // 32
#define CAP    96     // per-row candidate buffer capacity per fold interval
#define MARGIN 0.25f  // >= 2x max |d_approx - d_exact| (fp16 worst-case ~0.08)

typedef unsigned long long u64;
typedef unsigned short ushort_t;
typedef __attribute__((ext_vector_type(8))) _Float16 f16x8;  // 8 f16 = 4 VGPRs
typedef __attribute__((ext_vector_type(4))) float f32x4;

__device__ __forceinline__ u64 pack64(float d, int j) {
    // d >= 0 -> f32 bits order-preserving; u64 ascending == lex (d, j)
    return ((u64)__float_as_uint(d) << 32) | (unsigned)j;
}

// ---------------------------------------------------------------------------
// DPP-based 16-lane exchanges. All fold shuffles stay within a 16-lane group
// == one DPP row on CDNA; exec divergence is row-uniform, so DPP never reads
// inactive lanes. DPP direction convention (verified R5, passed): row_shr:N =
// dest[i] <- src[i-N]; row_shl:N = dest[i] <- src[i+N]. quad_perm (xor1/xor2)
// and row_mirror are direction-symmetric.
// ---------------------------------------------------------------------------
template<int CTRL>
__device__ __forceinline__ u64 dpp_u64(u64 x) {
    unsigned lo = (unsigned)x, hi = (unsigned)(x >> 32);
    lo = (unsigned)__builtin_amdgcn_update_dpp(0, (int)lo, CTRL, 0xF, 0xF, true);
    hi = (unsigned)__builtin_amdgcn_update_dpp(0, (int)hi, CTRL, 0xF, 0xF, true);
    return ((u64)hi << 32) | lo;
}
// quad_perm [1,0,3,2] = 0xB1 (xor1); [2,3,0,1] = 0x4E (xor2)
__device__ __forceinline__ u64 swap_xor1(u64 x) { return dpp_u64<0xB1>(x); }
__device__ __forceinline__ u64 swap_xor2(u64 x) { return dpp_u64<0x4E>(x); }
// xor4: (n&4)==0 lanes need src[n+4] -> row_shl:4 (0x104);
//       (n&4)!=0 lanes need src[n-4] -> row_shr:4 (0x114)
__device__ __forceinline__ u64 swap_xor4(u64 x, int n) {
    u64 shr = dpp_u64<0x114>(x);   // src[n-4]
    u64 shl = dpp_u64<0x104>(x);   // src[n+4]
    return (n & 4) ? shr : shl;
}
// xor8: (n&8)==0 -> row_shl:8 (0x108) = src[n+8]; else row_shr:8 (0x118) = src[n-8]
__device__ __forceinline__ u64 swap_xor8(u64 x, int n) {
    u64 shr = dpp_u64<0x118>(x);   // src[n-8]
    u64 shl = dpp_u64<0x108>(x);   // src[n+8]
    return (n & 8) ? shr : shl;
}
// xor15 within 16-lane row: row_mirror (0x140)
__device__ __forceinline__ u64 swap_mirror(u64 x) { return dpp_u64<0x140>(x); }

// compare-exchange stages (ascending bitonic over lanes n=0..15)
#define CEK(x, J, K, SW)                                                      \
    { u64 px = SW; bool wmin = ((n & (J)) == 0) == ((n & (K)) == 0);          \
      x = (wmin == (px < x)) ? px : x; }
#define CEA(L, J, SW)                                                         \
    { u64 pl = SW; bool wmin = ((n & (J)) == 0);                              \
      L = (wmin == (pl < L)) ? pl : L; }
#define SORT16(x)                                                             \
    CEK(x, 1, 2,  swap_xor1(x))                                               \
    CEK(x, 2, 4,  swap_xor2(x))    CEK(x, 1, 4,  swap_xor1(x))                \
    CEK(x, 4, 8,  swap_xor4(x,n))  CEK(x, 2, 8,  swap_xor2(x))                \
    CEK(x, 1, 8,  swap_xor1(x))                                               \
    CEK(x, 8, 16, swap_xor8(x,n))  CEK(x, 4, 16, swap_xor4(x,n))              \
    CEK(x, 2, 16, swap_xor2(x))    CEK(x, 1, 16, swap_xor1(x))

// ---------------------------------------------------------------------------
// Kernel 1: prep. sq (exact ascending-k fmaf chain — recheck uses the same
// chain so dot(i,i)==sq[i] bit-exact => d(i,i)==0), transposed fp16 XtH
// (R6: single fp16 product replaces bf16 hi/lo Dekker triple — N(0,1) inputs
// fit fp16; worst-case d error ~0.08 <= MARGIN/2... covered, see knn notes),
// transposed fp32 Xt32 for recheck.
// ---------------------------------------------------------------------------
__global__ __launch_bounds__(256) void prep_kernel(const float* __restrict__ crd,
                                                   float* __restrict__ sq,
                                                   ushort_t* __restrict__ XtH,
                                                   float* __restrict__ Xt32) {
    const int f = blockIdx.x * 256 + threadIdx.x;
    float acc = 0.f;
#pragma unroll
    for (int kb = 0; kb < 8; ++kb) {
        ushort_t hb[8];
        float    xv[8];
#pragma unroll
        for (int u = 0; u < 8; ++u) {
            int k = kb * 8 + u;
            float x = crd[k * F + f];
            acc = fmaf(x, x, acc);
            hb[u] = __builtin_bit_cast(ushort_t, (_Float16)x);  // RTN f32->f16
            xv[u] = x;
        }
        *(uint4*)&XtH[(size_t)f * KD + kb * 8] = *(const uint4*)hb;
        *(float4*)&Xt32[(size_t)f * KD + kb * 8]     = *(const float4*)&xv[0];
        *(float4*)&Xt32[(size_t)f * KD + kb * 8 + 4] = *(const float4*)&xv[4];
    }
    sq[f] = acc;
}

// ---------------------------------------------------------------------------
// Kernel 2: MFMA distance + approx top-16 per (row, col-quarter).
// R5 post-mortem: MfmaUtil 11.9% == exact MFMA-time/wall for the bf16 hi/lo
// TRIPLE (10.7us of 83us). R6: fp16 single product — 4 MFMAs/round (was 12),
// half the B staging, ~32 VGPRs freed. Margin: fp16 per-term rel err 2^-11,
// |dot err| <= 2*2^-11*sum|x_k y_k| ~ 0.04 worst, d err <= 0.08; MARGIN 0.25
// >= 2x. Approx list only needs to CONTAIN true top-8; recheck is exact f32.
// Fold: wave-parallel DPP bitonic (R5-verified), ballot pre-skip vs the
// pass-start 16th-best (conservative — list only shrinks, skip is safe).
// ---------------------------------------------------------------------------
__global__ __launch_bounds__(256, 4) void knn_mfma(const ushort_t* __restrict__ XtH,
                                                   const float* __restrict__ sq,
                                                   u64* __restrict__ part) {
    __shared__ u64 buf[WROWS][CAP + 1];     // 24.8 KB
    __shared__ u64 lst[WROWS][MKEEP + 1];   // 4.4 KB
    __shared__ __align__(16) float thr[WROWS];
    __shared__ int cnt[WROWS];

    const int tid  = threadIdx.x;
    const int wave = tid >> 6;
    const int tx   = tid & 63;
    const int quad = tx >> 4;
    const int n    = tx & 15;
    const int blockRow = (blockIdx.x >> 2) * WROWS;
    const int jq    = blockIdx.x & 3;
    const int jbase = jq * (F / JQ);

    if (tid < WROWS) { cnt[tid] = 0; thr[tid] = __int_as_float(0x7f800000); }
#pragma unroll
    for (int e = tid; e < WROWS * MKEEP; e += 256) lst[e >> 4][e & 15] = ~0ULL;
    __syncthreads();

    // A fragments for both 16-row tiles, resident all sweep
    const size_t a0 = (size_t)(blockRow + n) * KD + quad * 8;
    const size_t a1 = (size_t)(blockRow + 16 + n) * KD + quad * 8;
    const f16x8 a0h0 = *(const f16x8*)(XtH + a0), a0h1 = *(const f16x8*)(XtH + a0 + 32);
    const f16x8 a1h0 = *(const f16x8*)(XtH + a1), a1h1 = *(const f16x8*)(XtH + a1 + 32);
    const f32x4 sqi0 = *(const f32x4*)&sq[blockRow + quad * 4];
    const f32x4 sqi1 = *(const f32x4*)&sq[blockRow + 16 + quad * 4];
    f32x4 pre0, pre1;   // 0.5*(sqi - thr); -inf => accept-all
#pragma unroll
    for (int r = 0; r < 4; ++r) { pre0[r] = -__int_as_float(0x7f800000);
                                  pre1[r] = -__int_as_float(0x7f800000); }

    const int laneCol = wave * 16 + n;    // col offset within a round's 64

#define LOADB(H0, H1, SJ, RND)                                                \
    {   int jc = jbase + (RND) * CPR + laneCol;                               \
        size_t bo = (size_t)jc * KD + quad * 8;                               \
        H0 = *(const f16x8*)(XtH + bo); H1 = *(const f16x8*)(XtH + bo + 32);  \
        SJ = sq[jc]; }

#define MFMABODY(H0, H1)                                                      \
        f32x4 za0 = {0,0,0,0}, za1 = {0,0,0,0};                               \
        za0 = __builtin_amdgcn_mfma_f32_16x16x32_f16(a0h0, H0, za0, 0, 0, 0); \
        za0 = __builtin_amdgcn_mfma_f32_16x16x32_f16(a0h1, H1, za0, 0, 0, 0); \
        za1 = __builtin_amdgcn_mfma_f32_16x16x32_f16(a1h0, H0, za1, 0, 0, 0); \
        za1 = __builtin_amdgcn_mfma_f32_16x16x32_f16(a1h1, H1, za1, 0, 0, 0);

// round 0: accept-all, deterministic slot = laneCol (no atomics)
#define PROCESS0(H0, H1, SJ, RND)                                             \
    {   MFMABODY(H0, H1)                                                      \
        const int jc = jbase + (RND) * CPR + laneCol;                         \
        _Pragma("unroll")                                                     \
        for (int r = 0; r < 4; ++r) {                                         \
            float d0 = fmaxf((sqi0[r] + SJ) - 2.f * za0[r], 0.f);             \
            buf[quad * 4 + r][laneCol] = pack64(d0, jc);                      \
            float d1 = fmaxf((sqi1[r] + SJ) - 2.f * za1[r], 0.f);             \
            buf[16 + quad * 4 + r][laneCol] = pack64(d1, jc);                 \
        } }

#define PROCESS(H0, H1, SJ, RND)                                              \
    {   MFMABODY(H0, H1)                                                      \
        const int jc = jbase + (RND) * CPR + laneCol;                         \
        const float h = 0.5f * SJ;                                            \
        _Pragma("unroll")                                                     \
        for (int r = 0; r < 4; ++r) {                                         \
            float dot = za0[r];                                               \
            if (dot >= pre0[r] + h) {                                         \
                float d = fmaxf((sqi0[r] + SJ) - 2.f * dot, 0.f);             \
                int row = quad * 4 + r;                                       \
                int q = atomicAdd(&cnt[row], 1);                              \
                if (q < CAP) buf[row][q] = pack64(d, jc);                     \
            }                                                                 \
            dot = za1[r];                                                     \
            if (dot >= pre1[r] + h) {                                         \
                float d = fmaxf((sqi1[r] + SJ) - 2.f * dot, 0.f);             \
                int row = 16 + quad * 4 + r;                                  \
                int q = atomicAdd(&cnt[row], 1);                              \
                if (q < CAP) buf[row][q] = pack64(d, jc);                     \
            }                                                                 \
        } }

// Wave-parallel fold, DPP stages. 16 lanes per row; lane n holds sorted list
// slot n. 16 rows per pass, 2 passes cover WROWS=32. Per 16-entry batch:
// ballot pre-skip vs pass-start 16th-best (conservative -> safe), bitonic
// sort-16 (10 DPP stages), merge Lv=min(Lv,mirror(batch)) + 4 clean stages.
#define FOLD(R0)                                                              \
    {   __syncthreads();                                                      \
        _Pragma("unroll")                                                     \
        for (int p = 0; p < 2; ++p) {                                         \
            const int row = p * 16 + wave * 4 + quad;                         \
            u64 Lv = lst[row][n];                                             \
            const u64 tmax = __shfl(Lv, (tx & 48) | 15, 64);                  \
            const int nn = (R0) ? CPR : min(cnt[row], CAP);                   \
            for (int ii = 0; ii < nn; ii += 16) {                             \
                u64 x = (ii + n < nn) ? buf[row][ii + n] : ~0ULL;             \
                u64 bal = __ballot(x < tmax);                                 \
                if ((unsigned short)(bal >> (quad * 16)) == 0) continue;      \
                SORT16(x)                                                     \
                u64 xr = swap_mirror(x);      /* reverse within 16 */         \
                Lv = (xr < Lv) ? xr : Lv;     /* bitonic now */               \
                CEA(Lv, 8, swap_xor8(Lv, n))                                  \
                CEA(Lv, 4, swap_xor4(Lv, n))                                  \
                CEA(Lv, 2, swap_xor2(Lv))                                     \
                CEA(Lv, 1, swap_xor1(Lv))                                     \
            }                                                                 \
            lst[row][n] = Lv;                                                 \
            if (n == NB - 1) thr[row] = __uint_as_float((unsigned)(Lv >> 32)) + MARGIN; \
            if (n == 0) cnt[row] = 0;                                         \
        }                                                                     \
        __syncthreads();                                                      \
        {   f32x4 t0 = *(const f32x4*)&thr[quad * 4];                         \
            f32x4 t1 = *(const f32x4*)&thr[16 + quad * 4];                    \
            _Pragma("unroll")                                                 \
            for (int r = 0; r < 4; ++r) {                                     \
                pre0[r] = 0.5f * (sqi0[r] - t0[r]);                           \
                pre1[r] = 0.5f * (sqi1[r] - t1[r]);                           \
            } } }

    f16x8 B0h0, B0h1, B1h0, B1h1;
    float B0sj, B1sj;
    LOADB(B0h0, B0h1, B0sj, 0)
    LOADB(B1h0, B1h1, B1sj, 1)

    PROCESS0(B0h0, B0h1, B0sj, 0)
    LOADB(B0h0, B0h1, B0sj, 2)
    FOLD(1)
    PROCESS(B1h0, B1h1, B1sj, 1)
    LOADB(B1h0, B1h1, B1sj, 3)
    FOLD(0)

    for (int rr = 2; rr < NROUND; rr += 2) {
        PROCESS(B0h0, B0h1, B0sj, rr)
        if (rr + 2 < NROUND) LOADB(B0h0, B0h1, B0sj, rr + 2)
        PROCESS(B1h0, B1h1, B1sj, rr + 1)
        if (rr + 3 < NROUND) LOADB(B1h0, B1h1, B1sj, rr + 3)
        if (((rr + 1) & (rr + 2)) == 0) FOLD(0)   // rounds 3,7,15,31
    }

    // write per-quarter top-16 lists (final fold happened at round 31)
#pragma unroll
    for (int e = tid; e < WROWS * MKEEP; e += 256) {
        int rrw = e >> 4, ss = e & 15;
        part[((size_t)jq * F + blockRow + rrw) * MKEEP + ss] = lst[rrw][ss];
    }
#undef LOADB
#undef MFMABODY
#undef PROCESS0
#undef PROCESS
#undef FOLD
}

// ---------------------------------------------------------------------------
// Kernel 3: exact recheck. Block = 4 rows x 64 candidates (one row per wave).
// B rows contiguous from Xt32 (256B/candidate, L2-hot); A row in LDS.
// Exact ascending-k fmaf chain (bit-identical to sq's => d(i,i)==0).
// Top-8 via in-register wave shuffle-pop on packed u64 -> exact jax tie-break.
// ---------------------------------------------------------------------------
__global__ __launch_bounds__(256) void recheck_kernel(const float* __restrict__ Xt32,
                                                      const float* __restrict__ sq,
                                                      const u64* __restrict__ part,
                                                      int* __restrict__ knn) {
    __shared__ float A_s[4][KD];
    const int tid = threadIdx.x;
    const int rl = tid >> 6, tx = tid & 63;
    const int i = blockIdx.x * 4 + rl;

    A_s[tid >> 6][tid & 63] = Xt32[(size_t)(blockIdx.x * 4 + (tid >> 6)) * KD + (tid & 63)];
    __syncthreads();

    u64 pc = part[((size_t)(tx >> 4) * F + i) * MKEEP + (tx & 15)];
    int j = (int)(pc & 0xffffffffu);

    const float4* b4 = (const float4*)(Xt32 + (size_t)j * KD);
    float acc = 0.f;
#pragma unroll
    for (int kk = 0; kk < KD / 4; ++kk) {
        float4 b = b4[kk];
        const float* a = &A_s[rl][kk * 4];
        acc = fmaf(a[0], b.x, acc);
        acc = fmaf(a[1], b.y, acc);
        acc = fmaf(a[2], b.z, acc);
        acc = fmaf(a[3], b.w, acc);
    }
    float d = fmaxf((sq[i] + sq[j]) - 2.f * acc, 0.f);
    u64 mine = pack64(d, j);

    int myout = 0;
#pragma unroll
    for (int s = 0; s < NB; ++s) {
        u64 m = mine;
#pragma unroll
        for (int off = 32; off >= 1; off >>= 1) {
            u64 o = __shfl_xor(m, off, 64);
            if (o < m) m = o;
        }
        if (mine == m) mine = ~0ULL;       // pop (unique (d,j) per row)
        if (tx == s) myout = (int)(m & 0xffffffffu);
    }
    if (tx < NB) knn[(size_t)i * NB + tx] = myout;
}

// ---------------------------------------------------------------------------
// Kernel 4: gather. 4 blocks per (b,c); row staged in LDS; int4 knn +
// float4 stores, coalesced.
// ---------------------------------------------------------------------------
__global__ __launch_bounds__(512) void gather_kernel(const float* __restrict__ inp,
                                                     const int* __restrict__ knn,
                                                     float* __restrict__ out) {
    __shared__ float row[F];    // 32 KB
    const int bc    = blockIdx.x >> 2;
    const int chunk = blockIdx.x & 3;
    const int tid   = threadIdx.x;

    const float4* in4  = (const float4*)(inp + (size_t)bc * F);
    float4*       row4 = (float4*)row;
#pragma unroll
    for (int i = 0; i < (F / 4) / 512; ++i) row4[i * 512 + tid] = in4[i * 512 + tid];
    __syncthreads();

    const int4* kn4 = (const int4*)knn;
    float4*     ou4 = (float4*)(out + (size_t)bc * (F * NB));

#pragma unroll
    for (int i = 0; i < 8; ++i) {
        int e = chunk * 4096 + i * 512 + tid;
        int4 idx = kn4[e];
        if (e == 0) idx.x = 0;             // flat_idx[0] hardcoded 0
        float4 o;
        o.x = row[idx.x]; o.y = row[idx.y]; o.z = row[idx.z]; o.w = row[idx.w];
        ou4[e] = o;
    }
}

extern "C" void kernel_launch(void* const* d_in, const int* in_sizes, int n_in,
                              void* d_out, int out_size, void* d_ws, size_t ws_size,
                              hipStream_t stream) {
    const float* inp = (const float*)d_in[0];   // (64,4,8192,1) fp32
    const float* crd = (const float*)d_in[1];   // (64,1,8192)  fp32
    float* out = (float*)d_out;                 // (64,4,65536,1) fp32

    ushort_t* XtH  = (ushort_t*)d_ws;                               // 1 MB (fp16)
    float*    Xt32 = (float*)((char*)d_ws + (2u << 20));            // 2 MB
    float*    sq   = (float*)((char*)d_ws + (4u << 20));            // 32 KB
    int*      knn  = (int*)((char*)d_ws + (4u << 20) + (1u << 15)); // 256 KB
    u64*      part = (u64*)((char*)d_ws + (5u << 20));              // 4 MB

    prep_kernel<<<F / 256, 256, 0, stream>>>(crd, sq, XtH, Xt32);
    knn_mfma<<<(F / WROWS) * JQ, 256, 0, stream>>>(XtH, sq, part);
    recheck_kernel<<<F / 4, 256, 0, stream>>>(Xt32, sq, part, knn);
    gather_kernel<<<256 * 4, 512, 0, stream>>>(inp, knn, out);
}